// Round 1
// 107154.639 us; speedup vs baseline: 1.3117x; 1.3117x over previous
//
#include <hip/hip_runtime.h>
#include <math.h>

// Problem constants
static constexpr int S_LEN = 512;
static constexpr int BATCH = 256;
static constexpr int IDIM  = 256;
static constexpr int HDIM  = 1024;
static constexpr int SWID  = 256;
static constexpr int SDEP  = 100;
static constexpr int K1    = IDIM + SWID;   // 512
static constexpr int KTOT  = K1 + HDIM;     // 1536

static constexpr int NBLK = 256;
static constexpr int NTHR = 256;

// Phase A (gates GEMM) tile: 32 batches x 32 j x 4 gates, K-chunks of 16
static constexpr int A_BM = 32;
static constexpr int A_BJ = 32;
static constexpr int A_KB = 16;
static constexpr int A_NC = KTOT / A_KB;    // 96
static constexpr int A_LDA = A_BM + 4;      // 36
static constexpr int A_LDB = A_BJ * 4 + 4;  // 132

// Phase BC tile: 8 batches x 32 stack cols per block (32 x 8 = 256 blocks)
static constexpr int BC_BB = 8;
static constexpr int BC_BJ = 32;
static constexpr int BC_KB = 64;
static constexpr int BC_NC = HDIM / BC_KB;  // 16
static constexpr int BC_LDD = BC_BJ + 1;    // 33

struct SharedA {
    // 3-stage pipeline: loads issued 2 chunks ahead of their LDS store
    float As[3][A_KB][A_LDA];    // [buf][kk][b]
    float Bs[3][A_KB][A_LDB];    // [buf][kk][j*4+g]
};
struct SharedBC {
    float Hs[BC_BB][HDIM + 4];       // 8 x 1028
    float Dsh[2][BC_KB][BC_LDD];     // double-buffered [kk][j]
    float logits[BC_BB][3];
    float ctrl[BC_BB][3];            // push, pop, noop
};
union SharedU {
    SharedA a;
    SharedBC bc;
};

__device__ __forceinline__ float sigmoidf_(float v) {
    return 1.0f / (1.0f + expf(-v));
}

// Software grid barrier: monotonic counter, device(agent)-scope atomics.
// All 256 blocks are co-resident (1 block/CU on 256 CUs), so spinning is safe.
__device__ __forceinline__ void grid_barrier(unsigned* cnt, unsigned target) {
    __syncthreads();
    if (threadIdx.x == 0) {
        __threadfence();  // release all prior global writes (device scope)
        __hip_atomic_fetch_add(cnt, 1u, __ATOMIC_ACQ_REL, __HIP_MEMORY_SCOPE_AGENT);
        while (__hip_atomic_load(cnt, __ATOMIC_ACQUIRE, __HIP_MEMORY_SCOPE_AGENT) < target)
            __builtin_amdgcn_s_sleep(2);
        __threadfence();
    }
    __syncthreads();
}

__global__ void init_barrier_kernel(unsigned* cnt) {
    if (threadIdx.x == 0) *cnt = 0u;
}

__global__ __launch_bounds__(NTHR) void stackrnn_kernel(
    const float* __restrict__ x,
    const float* __restrict__ h0,
    const float* __restrict__ c0,
    const float* __restrict__ stack0,
    const float* __restrict__ W_ih,
    const float* __restrict__ W_hh,
    const float* __restrict__ b_ih,
    const float* __restrict__ b_hh,
    const float* __restrict__ A_w,
    const float* __restrict__ A_b,
    const float* __restrict__ D_w,
    const float* __restrict__ D_b,
    float* __restrict__ out,
    float* __restrict__ ws_stack,
    float* __restrict__ ws_c,
    unsigned* __restrict__ bar)
{
    __shared__ SharedU sm;
    const int tid = threadIdx.x;
    const int bid = blockIdx.x;
    const int gtid = bid * NTHR + tid;
    const int gstride = NBLK * NTHR;  // 65536
    unsigned bar_target = NBLK;

    // ---- Phase A thread-invariant indexing (hoisted out of t-loop) ----
    const int a_bt = bid >> 5;       // 0..7  : batch tile
    const int a_jt = bid & 31;       // 0..31 : j tile
    const int a_tx = tid & 31;       // j_local
    const int a_ty = tid >> 5;       // 0..7  : group of 4 batch rows
    const int a_bl = tid >> 3;       // 0..31
    const int a_kk = (tid & 7) * 2;  // 0,2,...,14
    const int b_cl = tid >> 1;       // 0..127 (= j_local*4 + gate)
    const int b_kb = (tid & 1) * 8;  // 0 or 8
    const int b_g  = b_cl & 3;
    const int b_jl = b_cl >> 2;
    const int b_col = b_g * HDIM + a_jt * A_BJ + b_jl;
    const int a_b = a_bt * A_BM + a_bl;
    const int a_j = a_jt * A_BJ + a_tx;
    const float bias_i = b_ih[0 * HDIM + a_j] + b_hh[0 * HDIM + a_j];
    const float bias_f = b_ih[1 * HDIM + a_j] + b_hh[1 * HDIM + a_j];
    const float bias_g = b_ih[2 * HDIM + a_j] + b_hh[2 * HDIM + a_j];
    const float bias_o = b_ih[3 * HDIM + a_j] + b_hh[3 * HDIM + a_j];

    // ---- Phase BC thread-invariant indexing ----
    const int c_bg = bid >> 3;       // 0..31 : batch group (8 batches)
    const int c_jg = bid & 7;        // 0..7  : col group (32 cols)
    const int c_tx = tid & 31;       // j_local
    const int c_ty = tid >> 5;       // 0..7  : b_local
    const int d_row = tid >> 3;      // 0..31
    const int d_kb  = (tid & 7) * 8; // 0..56
    const float d_bias = D_b[c_jg * BC_BJ + c_tx];

    // ---- init workspace state from stack0 / c0 (ws is poisoned every call) ----
    {
        const float4* src = (const float4*)stack0;
        float4* dst = (float4*)ws_stack;
        const int n4 = (BATCH * SDEP * SWID) / 4;
        for (int i = gtid; i < n4; i += gstride) dst[i] = src[i];
        const float4* src2 = (const float4*)c0;
        float4* dst2 = (float4*)ws_c;
        const int c4 = (BATCH * HDIM) / 4;
        for (int i = gtid; i < c4; i += gstride) dst2[i] = src2[i];
    }
    grid_barrier(bar, bar_target); bar_target += NBLK;

    for (int t = 0; t < S_LEN; ++t) {
        // ================= Phase A: gates GEMM + LSTM cell =================
        {
            const float* hprev = (t == 0) ? h0 : (out + (size_t)(t - 1) * BATCH * HDIM);
            const float* xbase = x + (size_t)t * BATCH * IDIM + (size_t)a_b * IDIM;
            const float* sbase = ws_stack + (size_t)a_b * SDEP * SWID;
            const float* hbase = hprev + (size_t)a_b * HDIM;

            float acc[4][4] = {};

            auto load_chunk = [&](int kc, float2& ra, float4& rb0, float4& rb1) {
                const int k0 = kc * A_KB;
                const int k = k0 + a_kk;
                if (k < IDIM)      ra = *(const float2*)(xbase + k);
                else if (k < K1)   ra = *(const float2*)(sbase + (k - IDIM));
                else               ra = *(const float2*)(hbase + (k - K1));
                const float* wsrc = (k0 < K1)
                    ? (W_ih + (size_t)b_col * K1 + (k0 + b_kb))
                    : (W_hh + (size_t)b_col * HDIM + (k0 - K1 + b_kb));
                rb0 = *(const float4*)(wsrc);
                rb1 = *(const float4*)(wsrc + 4);
            };
            auto store_chunk = [&](int b, const float2& ra, const float4& rb0, const float4& rb1) {
                float* pa = &sm.a.As[b][0][0];
                pa[a_kk * A_LDA + a_bl]       = ra.x;
                pa[(a_kk + 1) * A_LDA + a_bl] = ra.y;
                float* pb = &sm.a.Bs[b][0][0] + b_kb * A_LDB + b_cl;
                pb[0 * A_LDB] = rb0.x; pb[1 * A_LDB] = rb0.y;
                pb[2 * A_LDB] = rb0.z; pb[3 * A_LDB] = rb0.w;
                pb[4 * A_LDB] = rb1.x; pb[5 * A_LDB] = rb1.y;
                pb[6 * A_LDB] = rb1.z; pb[7 * A_LDB] = rb1.w;
            };
            auto compute_chunk = [&](int b) {
                const float* asb = &sm.a.As[b][0][0] + a_ty * 4;
                const float* bsb = &sm.a.Bs[b][0][0] + a_tx * 4;
                #pragma unroll
                for (int kk = 0; kk < A_KB; ++kk) {
                    const float4 av = *(const float4*)(asb + kk * A_LDA);
                    const float4 bv = *(const float4*)(bsb + kk * A_LDB);
                    acc[0][0] += av.x * bv.x; acc[0][1] += av.x * bv.y;
                    acc[0][2] += av.x * bv.z; acc[0][3] += av.x * bv.w;
                    acc[1][0] += av.y * bv.x; acc[1][1] += av.y * bv.y;
                    acc[1][2] += av.y * bv.z; acc[1][3] += av.y * bv.w;
                    acc[2][0] += av.z * bv.x; acc[2][1] += av.z * bv.y;
                    acc[2][2] += av.z * bv.z; acc[2][3] += av.z * bv.w;
                    acc[3][0] += av.w * bv.x; acc[3][1] += av.w * bv.y;
                    acc[3][2] += av.w * bv.z; acc[3][3] += av.w * bv.w;
                }
            };

            // prologue: chunk0 -> regsA -> buf0; chunk1 -> regsB (in flight)
            float2 raA, raB; float4 rb0A, rb1A, rb0B, rb1B;
            load_chunk(0, raA, rb0A, rb1A);
            store_chunk(0, raA, rb0A, rb1A);
            load_chunk(1, raB, rb0B, rb1B);
            __syncthreads();

            int b_cur = 0;
            for (int kp = 0; kp < A_NC / 2; ++kp) {
                // even chunk kcE = 2*kp (regsA holds chunk kcE+... loads issue 2 ahead)
                const int kcE = 2 * kp;
                if (kcE + 2 < A_NC) load_chunk(kcE + 2, raA, rb0A, rb1A);
                compute_chunk(b_cur);
                int b_nx = (b_cur == 2) ? 0 : b_cur + 1;
                store_chunk(b_nx, raB, rb0B, rb1B);   // chunk kcE+1 (always exists)
                __syncthreads();
                b_cur = b_nx;
                // odd chunk kcO = kcE+1
                const int kcO = kcE + 1;
                if (kcO + 2 < A_NC) load_chunk(kcO + 2, raB, rb0B, rb1B);
                compute_chunk(b_cur);
                b_nx = (b_cur == 2) ? 0 : b_cur + 1;
                if (kcO + 1 < A_NC) store_chunk(b_nx, raA, rb0A, rb1A);
                __syncthreads();
                b_cur = b_nx;
            }

            // LSTM epilogue
            float* outrow = out + (size_t)t * BATCH * HDIM;
            #pragma unroll
            for (int r = 0; r < 4; ++r) {
                const int b = a_bt * A_BM + a_ty * 4 + r;
                const float gi = sigmoidf_(acc[r][0] + bias_i);
                const float gf = sigmoidf_(acc[r][1] + bias_f);
                const float gg = tanhf(acc[r][2] + bias_g);
                const float go = sigmoidf_(acc[r][3] + bias_o);
                const size_t idx = (size_t)b * HDIM + a_j;
                const float cp = ws_c[idx];
                const float cn = gf * cp + gi * gg;
                const float hn = go * tanhf(cn);
                ws_c[idx] = cn;
                outrow[idx] = hn;
            }
        }
        grid_barrier(bar, bar_target); bar_target += NBLK;

        // ================= Phase BC: controls, d, stack update =================
        {
            const float* hcur = out + (size_t)t * BATCH * HDIM + (size_t)c_bg * BC_BB * HDIM;

            // stage h rows (8 x 1024)
            #pragma unroll
            for (int i = 0; i < BC_BB; ++i) {
                float4 v = *(const float4*)(hcur + (size_t)i * HDIM + tid * 4);
                *(float4*)&sm.bc.Hs[i][tid * 4] = v;
            }

            float4 rd0, rd1;
            auto d_load = [&](int kc) {
                const float* dsrc = D_w + (size_t)(c_jg * BC_BJ + d_row) * HDIM + kc * BC_KB + d_kb;
                rd0 = *(const float4*)dsrc;
                rd1 = *(const float4*)(dsrc + 4);
            };
            auto d_store = [&](int buf) {
                float* ds = &sm.bc.Dsh[buf][0][0] + d_kb * BC_LDD + d_row;
                ds[0 * BC_LDD] = rd0.x; ds[1 * BC_LDD] = rd0.y;
                ds[2 * BC_LDD] = rd0.z; ds[3 * BC_LDD] = rd0.w;
                ds[4 * BC_LDD] = rd1.x; ds[5 * BC_LDD] = rd1.y;
                ds[6 * BC_LDD] = rd1.z; ds[7 * BC_LDD] = rd1.w;
            };

            d_load(0);           // chunk-0 D_w loads fly under the logits loop
            __syncthreads();     // Hs visible

            // control logits: partial dot over k-chunk tx*32..+31, reduce over tx
            {
                float p0 = 0.f, p1 = 0.f, p2 = 0.f;
                const int kbase = c_tx * 32;
                #pragma unroll
                for (int kk = 0; kk < 32; ++kk) {
                    const float h = sm.bc.Hs[c_ty][kbase + kk];
                    p0 += h * A_w[0 * HDIM + kbase + kk];
                    p1 += h * A_w[1 * HDIM + kbase + kk];
                    p2 += h * A_w[2 * HDIM + kbase + kk];
                }
                #pragma unroll
                for (int off = 16; off > 0; off >>= 1) {
                    p0 += __shfl_xor(p0, off, 64);
                    p1 += __shfl_xor(p1, off, 64);
                    p2 += __shfl_xor(p2, off, 64);
                }
                if (c_tx == 0) {
                    sm.bc.logits[c_ty][0] = p0;
                    sm.bc.logits[c_ty][1] = p1;
                    sm.bc.logits[c_ty][2] = p2;
                }
            }
            d_store(0);
            __syncthreads();     // Dsh[0] + logits visible

            // D projection tile: d[b=c_ty][j=c_jg*32+c_tx], double-buffered over K
            float dacc = 0.0f;
            for (int kc = 0; kc < BC_NC; ++kc) {
                const int cur = kc & 1;
                if (kc + 1 < BC_NC) d_load(kc + 1);
                const float* hsrow = &sm.bc.Hs[c_ty][kc * BC_KB];
                const float* dcol  = &sm.bc.Dsh[cur][0][0] + c_tx;
                #pragma unroll
                for (int kk = 0; kk < BC_KB; ++kk)
                    dacc += hsrow[kk] * dcol[kk * BC_LDD];
                if (kc + 1 < BC_NC) d_store(cur ^ 1);
                __syncthreads();
            }
            const float dval = tanhf(dacc + d_bias);

            // softmax over 3 logits per batch
            if (tid < BC_BB) {
                const float l0 = sm.bc.logits[tid][0] + A_b[0];
                const float l1 = sm.bc.logits[tid][1] + A_b[1];
                const float l2 = sm.bc.logits[tid][2] + A_b[2];
                const float m = fmaxf(l0, fmaxf(l1, l2));
                const float e0 = expf(l0 - m), e1 = expf(l1 - m), e2 = expf(l2 - m);
                const float inv = 1.0f / (e0 + e1 + e2);
                sm.bc.ctrl[tid][0] = e0 * inv;   // push
                sm.bc.ctrl[tid][1] = e1 * inv;   // pop
                sm.bc.ctrl[tid][2] = e2 * inv;   // noop
            }
            __syncthreads();

            // stack update: thread owns column (b, j) over all depths (in-place),
            // 4-wide batched loads to break the dependent-load chain
            {
                const int b = c_bg * BC_BB + c_ty;
                const int jj = c_jg * BC_BJ + c_tx;
                const float a_push = sm.bc.ctrl[c_ty][0];
                const float a_pop  = sm.bc.ctrl[c_ty][1];
                const float a_noop = sm.bc.ctrl[c_ty][2];
                float* scol = ws_stack + (size_t)b * SDEP * SWID + jj;
                float prev = dval;            // stack_up[0] = d
                float cur = scol[0];
                for (int k0 = 0; k0 < SDEP; k0 += 4) {
                    const float n1 = scol[(size_t)(k0 + 1) * SWID];
                    const float n2 = scol[(size_t)(k0 + 2) * SWID];
                    const float n3 = scol[(size_t)(k0 + 3) * SWID];
                    const float n4 = (k0 + 4 < SDEP) ? scol[(size_t)(k0 + 4) * SWID] : 0.0f;
                    scol[(size_t)(k0 + 0) * SWID] = a_noop * cur + a_push * prev + a_pop * n1;
                    scol[(size_t)(k0 + 1) * SWID] = a_noop * n1  + a_push * cur  + a_pop * n2;
                    scol[(size_t)(k0 + 2) * SWID] = a_noop * n2  + a_push * n1   + a_pop * n3;
                    scol[(size_t)(k0 + 3) * SWID] = a_noop * n3  + a_push * n2   + a_pop * n4;
                    prev = n3;
                    cur = n4;
                }
            }
        }
        grid_barrier(bar, bar_target); bar_target += NBLK;
    }

    // ---- final outputs: hn, cn, stackn appended after outs ----
    {
        const size_t outs_sz = (size_t)S_LEN * BATCH * HDIM;
        const float4* hsrc = (const float4*)(out + (size_t)(S_LEN - 1) * BATCH * HDIM);
        float4* hdst = (float4*)(out + outs_sz);
        const int h4 = (BATCH * HDIM) / 4;
        for (int i = gtid; i < h4; i += gstride) hdst[i] = hsrc[i];
        const float4* csrc = (const float4*)ws_c;
        float4* cdst = (float4*)(out + outs_sz + (size_t)BATCH * HDIM);
        for (int i = gtid; i < h4; i += gstride) cdst[i] = csrc[i];
        const float4* ssrc = (const float4*)ws_stack;
        float4* sdst = (float4*)(out + outs_sz + 2 * (size_t)BATCH * HDIM);
        const int s4 = (BATCH * SDEP * SWID) / 4;
        for (int i = gtid; i < s4; i += gstride) sdst[i] = ssrc[i];
    }
}

extern "C" void kernel_launch(void* const* d_in, const int* in_sizes, int n_in,
                              void* d_out, int out_size, void* d_ws, size_t ws_size,
                              hipStream_t stream) {
    (void)in_sizes; (void)n_in; (void)out_size; (void)ws_size;
    const float* x      = (const float*)d_in[0];
    const float* h0     = (const float*)d_in[1];
    const float* c0     = (const float*)d_in[2];
    const float* stack0 = (const float*)d_in[3];
    const float* W_ih   = (const float*)d_in[4];
    const float* W_hh   = (const float*)d_in[5];
    const float* b_ih   = (const float*)d_in[6];
    const float* b_hh   = (const float*)d_in[7];
    const float* A_w    = (const float*)d_in[8];
    const float* A_b    = (const float*)d_in[9];
    const float* D_w    = (const float*)d_in[10];
    const float* D_b    = (const float*)d_in[11];
    float* out = (float*)d_out;
    float* ws_stack = (float*)d_ws;
    float* ws_c = ws_stack + (size_t)BATCH * SDEP * SWID;
    unsigned* bar = (unsigned*)(ws_c + (size_t)BATCH * HDIM);

    init_barrier_kernel<<<dim3(1), dim3(64), 0, stream>>>(bar);
    stackrnn_kernel<<<dim3(NBLK), dim3(NTHR), 0, stream>>>(
        x, h0, c0, stack0, W_ih, W_hh, b_ih, b_hh,
        A_w, A_b, D_w, D_b, out, ws_stack, ws_c, bar);
}